// Round 4
// baseline (86.697 us; speedup 1.0000x reference)
//
#include <hip/hip_runtime.h>

constexpr int NUM_HEADS      = 32;
constexpr int HEAD_DIM       = 128;
constexpr int NUM_KV         = 8;
constexpr int GROUP          = 4;                     // query heads per kv head
constexpr int BLOCK_SIZE     = 16;
constexpr int BLOCKS_PER_SEQ = 64;
constexpr int BATCH          = 64;
constexpr int SEQ            = BLOCKS_PER_SEQ * BLOCK_SIZE;   // 1024
constexpr int KV_ROW         = NUM_KV * HEAD_DIM;             // 1024 floats / slot-row
constexpr int SPLIT          = 8;                    // flash-decode partitions
constexpr int TOK            = SEQ / SPLIT;          // 128 tokens per partition
constexpr int TPW            = TOK / 4;              // 32 tokens per wave
constexpr float SCALE        = 0.08838834764831845f;

// workspace layout (floats): unnormalized partial O, then m, then l
constexpr size_t WS_O = 0;
constexpr size_t WS_M = (size_t)BATCH * NUM_KV * SPLIT * GROUP * HEAD_DIM; // 2,097,152
constexpr size_t WS_L = WS_M + (size_t)BATCH * NUM_KV * SPLIT * GROUP;     // +16,384

// One wg (256 thr = 4 waves) per (b, kv_head, split). Each wave owns a
// 32-token slice end-to-end (scores -> in-wave softmax -> V accumulate) with
// NO workgroup barrier; one final barrier for the cross-wave rescale-reduce.
__global__ __launch_bounds__(256) void paged_attn_split(
    const float* __restrict__ q,            // [B, 32, 128]
    const float* __restrict__ knew,         // [B, 8, 128]
    const float* __restrict__ vnew,         // [B, 8, 128]
    const float* __restrict__ kcache,       // [4096, 16, 8, 128]
    const float* __restrict__ vcache,       // [4096, 16, 8, 128]
    const int*   __restrict__ slot_mapping, // [B]
    const int*   __restrict__ block_tables, // [B, 64]
    float*       __restrict__ ws)
{
    const int wg  = (int)blockIdx.x;        // ((b*KV + kvh)*SPLIT + sp)
    const int sp  = wg & (SPLIT - 1);
    const int bk  = wg >> 3;                // b*KV + kvh
    const int kvh = bk & 7;
    const int b   = bk >> 3;
    const int tid = (int)threadIdx.x;
    const int lane = tid & 63;
    const int w    = tid >> 6;              // wave id = token-slice owner

    __shared__ int   s_row[4][TPW];           // per-wave token -> source row
    __shared__ float s_p[4][TPW][GROUP];      // scores -> exp(score - m_w)
    __shared__ float s_o[4][GROUP][HEAD_DIM]; // per-wave partial O (8 KB)
    __shared__ float s_ml[4][GROUP][2];       // per-wave (m, l)

    // --- per-wave setup: token -> source row (reference scatters fresh k/v
    // into the cache before gathering; we redirect reads instead). Lane t<32
    // handles token w*32+t. No cross-wave sharing -> no barrier.
    if (lane < TPW) {
        int t   = w * TPW + lane;
        int blk = block_tables[b * BLOCKS_PER_SEQ + sp * (TOK / BLOCK_SIZE) + (t >> 4)];
        int slot = blk * BLOCK_SIZE + (t & 15);
        int r = slot;
        #pragma unroll
        for (int i = 0; i < BATCH; i += 4) {
            int4 sm = *reinterpret_cast<const int4*>(&slot_mapping[i]);
            if (sm.x == slot) r = -1 - i;
            if (sm.y == slot) r = -2 - i;
            if (sm.z == slot) r = -3 - i;
            if (sm.w == slot) r = -4 - i;
        }
        s_row[w][lane] = r;
    }

    const int h0 = kvh * GROUP;
    const size_t hoff = (size_t)kvh * HEAD_DIM;
    const int sub = lane >> 4;              // token sub-slot (0..3)
    const int sl  = lane & 15;              // 16 lanes cooperate per token

    float4 qa[GROUP], qb[GROUP];            // q[g][sl*8 .. sl*8+8)
    #pragma unroll
    for (int g = 0; g < GROUP; ++g) {
        const float* qp = q + ((size_t)b * NUM_HEADS + h0 + g) * HEAD_DIM + sl * 8;
        qa[g] = *reinterpret_cast<const float4*>(qp);
        qb[g] = *reinterpret_cast<const float4*>(qp + 4);
    }

    // ---- Phase 1 (wave-local): scores for this wave's 32 tokens ----
    #pragma unroll
    for (int it = 0; it < TPW / 4; ++it) {  // 8 iters, 4 tokens/iter
        int t = it * 4 + sub;
        int r = s_row[w][t];
        const float* krow = (r >= 0)
            ? kcache + (size_t)r * KV_ROW + hoff
            : knew   + (size_t)(-1 - r) * KV_ROW + hoff;
        float4 ka = *reinterpret_cast<const float4*>(krow + sl * 8);
        float4 kb = *reinterpret_cast<const float4*>(krow + sl * 8 + 4);
        float p[GROUP];
        #pragma unroll
        for (int g = 0; g < GROUP; ++g) {
            p[g] = qa[g].x * ka.x + qa[g].y * ka.y + qa[g].z * ka.z + qa[g].w * ka.w
                 + qb[g].x * kb.x + qb[g].y * kb.y + qb[g].z * kb.z + qb[g].w * kb.w;
        }
        #pragma unroll
        for (int off = 1; off < 16; off <<= 1) {
            #pragma unroll
            for (int g = 0; g < GROUP; ++g) p[g] += __shfl_xor(p[g], off);
        }
        if (sl == 0) {
            #pragma unroll
            for (int g = 0; g < GROUP; ++g) s_p[w][t][g] = p[g] * SCALE;
        }
    }

    // ---- Phase 2 (wave-local): softmax stats over 32 tokens, per head.
    // Two passes; in each, the two 32-lane halves handle two heads.
    #pragma unroll
    for (int gp = 0; gp < 2; ++gp) {
        int g = gp * 2 + (lane >> 5);
        float v = s_p[w][lane & 31][g];
        float m = v;
        #pragma unroll
        for (int off = 1; off < 32; off <<= 1) m = fmaxf(m, __shfl_xor(m, off));
        float e = __expf(v - m);
        s_p[w][lane & 31][g] = e;
        float s = e;
        #pragma unroll
        for (int off = 1; off < 32; off <<= 1) s += __shfl_xor(s, off);
        if ((lane & 31) == 0) {
            s_ml[w][g][0] = m;
            s_ml[w][g][1] = s;
        }
    }

    // ---- Phase 3 (wave-local): O_w = sum_t e[t] * V[t]. Half-wave per V
    // row, float4/lane; acc = 4 dims x 4 heads in registers.
    {
        const int half = lane >> 5;
        const int dl   = lane & 31;         // dims [dl*4, dl*4+4)
        float4 a0 = {0,0,0,0}, a1 = a0, a2 = a0, a3 = a0;
        #pragma unroll 8
        for (int i = 0; i < TPW / 2; ++i) { // 16 iters, 2 tokens/iter
            int t = i * 2 + half;
            int r = s_row[w][t];
            const float* vrow = (r >= 0)
                ? vcache + (size_t)r * KV_ROW + hoff
                : vnew   + (size_t)(-1 - r) * KV_ROW + hoff;
            float4 vv = *reinterpret_cast<const float4*>(vrow + dl * 4);
            float4 pv = *reinterpret_cast<const float4*>(&s_p[w][t][0]);
            a0.x += pv.x * vv.x; a0.y += pv.x * vv.y; a0.z += pv.x * vv.z; a0.w += pv.x * vv.w;
            a1.x += pv.y * vv.x; a1.y += pv.y * vv.y; a1.z += pv.y * vv.z; a1.w += pv.y * vv.w;
            a2.x += pv.z * vv.x; a2.y += pv.z * vv.y; a2.z += pv.z * vv.z; a2.w += pv.z * vv.w;
            a3.x += pv.w * vv.x; a3.y += pv.w * vv.y; a3.z += pv.w * vv.z; a3.w += pv.w * vv.w;
        }
        #define RED4(A) A.x += __shfl_xor(A.x, 32); A.y += __shfl_xor(A.y, 32); \
                        A.z += __shfl_xor(A.z, 32); A.w += __shfl_xor(A.w, 32);
        RED4(a0) RED4(a1) RED4(a2) RED4(a3)
        #undef RED4
        if (half == 0) {
            *reinterpret_cast<float4*>(&s_o[w][0][dl * 4]) = a0;
            *reinterpret_cast<float4*>(&s_o[w][1][dl * 4]) = a1;
            *reinterpret_cast<float4*>(&s_o[w][2][dl * 4]) = a2;
            *reinterpret_cast<float4*>(&s_o[w][3][dl * 4]) = a3;
        }
    }

    __syncthreads();   // the ONLY barrier: publish s_o / s_ml across waves

    // ---- Cross-wave rescale-reduce; write chunk partial (m_c, l_c, O_c) ----
    {
        const int g = w;                    // wave = head
        float mw[4], lw[4], mc = -1e30f;
        #pragma unroll
        for (int u = 0; u < 4; ++u) {
            mw[u] = s_ml[u][g][0];
            lw[u] = s_ml[u][g][1];
            mc = fmaxf(mc, mw[u]);
        }
        float ew[4], L = 0.f;
        #pragma unroll
        for (int u = 0; u < 4; ++u) {
            ew[u] = __expf(mw[u] - mc);
            L += ew[u] * lw[u];
        }
        const int d = lane * 2;
        float ox = 0.f, oy = 0.f;
        #pragma unroll
        for (int u = 0; u < 4; ++u) {
            ox += ew[u] * s_o[u][g][d];
            oy += ew[u] * s_o[u][g][d + 1];
        }
        *reinterpret_cast<float2*>(
            ws + WS_O + ((size_t)wg * GROUP + g) * HEAD_DIM + d) = make_float2(ox, oy);
        if (lane == 0) {
            ws[WS_M + (size_t)wg * GROUP + g] = mc;
            ws[WS_L + (size_t)wg * GROUP + g] = L;
        }
    }
}

// Log-sum-exp combine of SPLIT partials per (b, kvh, g). 2048 blocks x 128 thr.
__global__ __launch_bounds__(128) void paged_attn_combine(
    const float* __restrict__ ws, float* __restrict__ out)
{
    const int hb  = (int)blockIdx.x;        // (b*KV+kvh)*GROUP + g
    const int g   = hb & 3;
    const int bk  = hb >> 2;
    const int kvh = bk & 7;
    const int b   = bk >> 3;
    const int d   = (int)threadIdx.x;

    float m[SPLIT];
    float mstar = -1e30f;
    #pragma unroll
    for (int s = 0; s < SPLIT; ++s) {
        m[s] = ws[WS_M + ((size_t)(bk * SPLIT + s) * GROUP) + g];
        mstar = fmaxf(mstar, m[s]);
    }
    float L = 0.f, acc = 0.f;
    #pragma unroll
    for (int s = 0; s < SPLIT; ++s) {
        float wgt = __expf(m[s] - mstar);
        L   += wgt * ws[WS_L + ((size_t)(bk * SPLIT + s) * GROUP) + g];
        acc += wgt * ws[WS_O + ((size_t)(bk * SPLIT + s) * GROUP + g) * HEAD_DIM + d];
    }
    out[((size_t)b * NUM_HEADS + kvh * GROUP + g) * HEAD_DIM + d] = acc / L;
}

extern "C" void kernel_launch(void* const* d_in, const int* in_sizes, int n_in,
                              void* d_out, int out_size, void* d_ws, size_t ws_size,
                              hipStream_t stream) {
    const float* q    = (const float*)d_in[0];
    const float* knew = (const float*)d_in[1];
    const float* vnew = (const float*)d_in[2];
    const float* kc   = (const float*)d_in[3];
    const float* vc   = (const float*)d_in[4];
    const int*   slot = (const int*)d_in[5];
    const int*   bt   = (const int*)d_in[6];
    float* out = (float*)d_out;
    float* ws  = (float*)d_ws;   // needs 8.5 MB

    hipLaunchKernelGGL(paged_attn_split, dim3(BATCH * NUM_KV * SPLIT), dim3(256),
                       0, stream, q, knew, vnew, kc, vc, slot, bt, ws);
    hipLaunchKernelGGL(paged_attn_combine, dim3(BATCH * NUM_KV * GROUP), dim3(128),
                       0, stream, ws, out);
}